// Round 3
// baseline (146.473 us; speedup 1.0000x reference)
//
#include <hip/hip_runtime.h>
#include <math.h>

#define N_TOK 8192
#define DDIM  768
#define NEXP  16

typedef float f32x4 __attribute__((ext_vector_type(4)));  // clang-native vec4

// Output layout (floats), concatenated in reference return order:
// y[N,D] | soft_avg[16] | hard_avg[16] | s_concat[N,16] | scalar 0
#define SOFT_OFF (N_TOK*DDIM)
#define HARD_OFF (SOFT_OFF + NEXP)
#define S_OFF    (HARD_OFF + NEXP)
#define SCAL_OFF (S_OFF + N_TOK*NEXP)

// d_ws layout: ws[0..15] = soft sums, ws[16..31] = hard counts.
// d_ws is NOT re-poisoned between graph replays and our atomics mutate it,
// so it must be zeroed at the start of every call.
extern "C" __global__ void init_ws_kernel(float* __restrict__ ws) {
  int t = threadIdx.x;
  if (t < 2*NEXP) ws[t] = 0.0f;
}

extern "C" __global__ void finalize_kernel(const float* __restrict__ ws,
                                           float* __restrict__ out) {
  int t = threadIdx.x;
  if (t < 2*NEXP) out[SOFT_OFF + t] = ws[t] * (1.0f/N_TOK);
  if (t == 0) out[SCAL_OFF] = 0.0f;
}

extern "C" __global__ __launch_bounds__(256) void fused_kernel(
    const float* __restrict__ f, const float* __restrict__ x,
    const float* __restrict__ W, const float* __restrict__ bias,
    float* __restrict__ out, float* __restrict__ ws) {
  const int n   = blockIdx.x;
  const int tid = threadIdx.x;
  __shared__ float xs[DDIM];
  __shared__ float part[256];
  __shared__ float lg[NEXP];

  // ---- Phase A1: stage x[n,:] into LDS (192 coalesced float4 loads) ----
  if (tid < DDIM/4)
    ((f32x4*)xs)[tid] = ((const f32x4*)(x + (size_t)n*DDIM))[tid];
  __syncthreads();

  // ---- Phase A2: gate partial dot-products ----
  // e in the LOW lane bits: the 16 e-lanes of one c read the SAME xs address
  // (broadcast, free); distinct c addresses land on 2 banks = 2-way (free).
  {
    const int e = tid & 15;      // expert
    const int c = tid >> 4;      // d-chunk (48 elements each)
    const f32x4* wrow = (const f32x4*)(W + e*DDIM + c*48);  // L2-hot, 48KB
    const f32x4* xrow = (const f32x4*)(xs + c*48);
    float acc = 0.f;
    #pragma unroll
    for (int j = 0; j < 12; ++j) {
      f32x4 wv = wrow[j];
      f32x4 xv = xrow[j];
      acc = fmaf(xv.x, wv.x, acc); acc = fmaf(xv.y, wv.y, acc);
      acc = fmaf(xv.z, wv.z, acc); acc = fmaf(xv.w, wv.w, acc);
    }
    part[tid] = acc;             // part[c*16 + e]
  }
  __syncthreads();
  if (tid < NEXP) {
    float s = bias[tid];
    #pragma unroll
    for (int c = 0; c < 16; ++c) s += part[c*16 + tid];
    lg[tid] = s;                 // logits, bank-spread reads (no conflict)
  }
  __syncthreads();

  // ---- Phase A3: top-2 + softmax, computed uniformly by every thread ----
  // Strict > keeps the lowest index on ties, matching jax.lax.top_k.
  float v0 = -INFINITY, v1 = -INFINITY;
  int e0 = 0, e1 = 0;
  #pragma unroll
  for (int j = 0; j < NEXP; ++j) {
    float val = lg[j];           // LDS broadcast — uniform across the wave
    if (val > v0) { v1 = v0; e1 = e0; v0 = val; e0 = j; }
    else if (val > v1) { v1 = val; e1 = j; }
  }
  float t1  = expf(v1 - v0);
  float inv = 1.0f / (1.0f + t1);
  float w0  = inv;
  float w1  = t1 * inv;

  // metrics: s_concat row + 2-4 fire-and-forget atomics per block
  if (tid < NEXP) {
    float g  = (tid == e0) ? w0 : ((tid == e1) ? w1 : 0.0f);
    bool sel = (g >= 1e-5f);     // s = 1 iff g < eps
    out[S_OFF + (size_t)n*NEXP + tid] = sel ? 0.0f : 1.0f;
    if (tid == e0 || tid == e1) {
      atomicAdd(&ws[tid], g);
      if (sel) atomicAdd(&ws[NEXP + tid], 1.0f);
    }
  }
  // No barrier needed: phase B depends only on uniform registers e0,e1,w0,w1.

  // ---- Phase B: stream f[n,:,:], fully coalesced 1KiB-per-wave float4 ----
  const int jg = (tid & 3) * 4;  // this thread's expert sub-quad
  float gx = (jg+0 == e0) ? w0 : ((jg+0 == e1) ? w1 : 0.0f);
  float gy = (jg+1 == e0) ? w0 : ((jg+1 == e1) ? w1 : 0.0f);
  float gz = (jg+2 == e0) ? w0 : ((jg+2 == e1) ? w1 : 0.0f);
  float gw = (jg+3 == e0) ? w0 : ((jg+3 == e1) ? w1 : 0.0f);
  const f32x4* fp = (const f32x4*)(f + (size_t)n * (DDIM*NEXP));
  float* yr = out + (size_t)n * DDIM;
  #pragma unroll
  for (int k = 0; k < 12; ++k) {
    int q = tid + 256*k;
    f32x4 v = __builtin_nontemporal_load(fp + q);   // zero-reuse stream
    float p = v.x*gx + v.y*gy + v.z*gz + v.w*gw;
    p += __shfl_xor(p, 1);       // 4 consecutive lanes hold one d
    p += __shfl_xor(p, 2);
    if ((tid & 3) == 0) {
      // 16 lanes/wave store 16 consecutive floats = contiguous 64B
      __builtin_nontemporal_store(p, yr + (q >> 2));
    }
  }
}

extern "C" void kernel_launch(void* const* d_in, const int* in_sizes, int n_in,
                              void* d_out, int out_size, void* d_ws, size_t ws_size,
                              hipStream_t stream) {
  const float* f = (const float*)d_in[0];   // [N, D, E]
  const float* x = (const float*)d_in[1];   // [N, D]
  const float* W = (const float*)d_in[2];   // [E, D]
  const float* b = (const float*)d_in[3];   // [E]
  float* out = (float*)d_out;
  float* ws  = (float*)d_ws;

  hipLaunchKernelGGL(init_ws_kernel, dim3(1), dim3(64), 0, stream, ws);
  hipLaunchKernelGGL(fused_kernel, dim3(N_TOK), dim3(256), 0, stream,
                     f, x, W, b, out, ws);
  hipLaunchKernelGGL(finalize_kernel, dim3(1), dim3(64), 0, stream, ws, out);
}

// Round 5
// 118.513 us; speedup vs baseline: 1.2359x; 1.2359x over previous
//
#include <hip/hip_runtime.h>
#include <math.h>

#define N_TOK 8192
#define DDIM  768
#define NEXP  16
#define WPAD  17   // Wl row stride in floats: makes c-stride 816 ≡ 16 (mod 32)
                   // -> a wave's 64 b128 slots tile all 32 banks 8-deep = conflict-free

typedef float f32x4 __attribute__((ext_vector_type(4)));

// Output layout (floats), concatenated in reference return order:
// y[N,D] | soft_avg[16] | hard_avg[16] | s_concat[N,16] | scalar 0
#define SOFT_OFF (N_TOK*DDIM)
#define HARD_OFF (SOFT_OFF + NEXP)
#define S_OFF    (HARD_OFF + NEXP)
#define SCAL_OFF (S_OFF + N_TOK*NEXP)

// d_ws layout: ws[0..15] raw soft sums | ws[16..31] raw hard counts |
//              ws[32..] per-token table {e0,e1,w0,w1} (f32x4, 16B-aligned).
// ws is mutated by our atomics and NOT re-poisoned between replays -> zero it
// every call (init_ws_kernel) for graph-replay determinism.
extern "C" __global__ void init_ws_kernel(float* __restrict__ ws) {
  if (threadIdx.x < 32) ws[threadIdx.x] = 0.0f;
}

__device__ __forceinline__ void fma4(f32x4& a, float s, f32x4 w) {
  a.x = fmaf(s, w.x, a.x);
  a.y = fmaf(s, w.y, a.y);
  a.z = fmaf(s, w.z, a.z);
  a.w = fmaf(s, w.w, a.w);
}

__device__ __forceinline__ float xred(float v) {
  // reduce across the 16 d-chunks: c lives in lane bits 2..5
  v += __shfl_xor(v, 4);
  v += __shfl_xor(v, 8);
  v += __shfl_xor(v, 16);
  v += __shfl_xor(v, 32);
  return v;
}

__device__ __forceinline__ void finish_token(
    int n, f32x4 av, int lane, float* __restrict__ out,
    f32x4* __restrict__ table, float* s_soft, float* s_hard) {
  // gather all 16 logits (lane q<4 holds expert quad 4q..4q+3); uniform result
  float v[16];
  #pragma unroll
  for (int q = 0; q < 4; ++q) {
    v[q*4+0] = __shfl(av.x, q);
    v[q*4+1] = __shfl(av.y, q);
    v[q*4+2] = __shfl(av.z, q);
    v[q*4+3] = __shfl(av.w, q);
  }
  // top-2, stable (strict > keeps lowest index on ties, matching lax.top_k)
  float v0 = -INFINITY, v1 = -INFINITY;
  int e0 = 0, e1 = 0;
  #pragma unroll
  for (int j = 0; j < 16; ++j) {
    float val = v[j];
    if (val > v0) { v1 = v0; e1 = e0; v0 = val; e0 = j; }
    else if (val > v1) { v1 = val; e1 = j; }
  }
  float t1  = expf(v1 - v0);
  float inv = 1.0f / (1.0f + t1);
  float w0  = inv;
  float w1  = t1 * inv;
  if (lane == 0) {
    f32x4 rec;
    rec.x = __int_as_float(e0); rec.y = __int_as_float(e1);
    rec.z = w0; rec.w = w1;
    table[n] = rec;
  }
  if (lane < NEXP) {
    float g  = (lane == e0) ? w0 : ((lane == e1) ? w1 : 0.0f);
    bool sel = (g >= 1e-5f);                       // s = 1 iff g < eps
    out[S_OFF + (size_t)n*NEXP + lane] = sel ? 0.0f : 1.0f;
    atomicAdd(&s_soft[lane], g);
    if (sel) atomicAdd(&s_hard[lane], 1.0f);
  }
}

extern "C" __global__ __launch_bounds__(256) void gate_kernel(
    const float* __restrict__ x, const float* __restrict__ W,
    const float* __restrict__ bias, float* __restrict__ out,
    float* __restrict__ ws) {
  __shared__ float Wl[DDIM*WPAD];   // 52.2 KB -> 2 blocks/CU, 8 waves/CU
  __shared__ float s_soft[NEXP];
  __shared__ float s_hard[NEXP];
  f32x4* table = (f32x4*)(ws + 32);
  int tid = threadIdx.x;
  if (tid < NEXP) { s_soft[tid] = 0.0f; s_hard[tid] = 0.0f; }
  for (int idx = tid; idx < DDIM*NEXP; idx += 256) {
    int e = idx / DDIM;             // coalesced global read of W[idx]
    int d = idx - e*DDIM;
    Wl[d*WPAD + e] = W[idx];        // transpose into padded LDS
  }
  __syncthreads();

  int wave = tid >> 6;
  int lane = tid & 63;
  int e4 = lane & 3;                // expert quad 0..3
  int c  = lane >> 2;               // d-chunk 0..15 (48 d's each)
  f32x4 bq = ((const f32x4*)bias)[e4];

  #pragma unroll
  for (int p = 0; p < 2; ++p) {
    int pairi = (blockIdx.x*4 + wave) + p*2048;   // 512 blocks * 4 waves * 2
    int n0 = pairi*2, n1 = n0 + 1;                // 2 tokens share W reads
    const float* x0p = x + (size_t)n0*DDIM + c*48;
    const float* x1p = x + (size_t)n1*DDIM + c*48;
    const float* wbase = &Wl[(c*48)*WPAD + 4*e4];
    f32x4 a0 = {0.f,0.f,0.f,0.f};
    f32x4 a1 = {0.f,0.f,0.f,0.f};
    #pragma unroll
    for (int m = 0; m < 12; ++m) {
      f32x4 xv0 = *(const f32x4*)(x0p + 4*m);
      f32x4 xv1 = *(const f32x4*)(x1p + 4*m);
      const float* wb = wbase + m*4*WPAD;
      f32x4 wq0 = *(const f32x4*)(wb);            // expert quad at d = 4m
      f32x4 wq1 = *(const f32x4*)(wb + WPAD);     // d = 4m+1
      f32x4 wq2 = *(const f32x4*)(wb + 2*WPAD);   // d = 4m+2
      f32x4 wq3 = *(const f32x4*)(wb + 3*WPAD);   // d = 4m+3
      fma4(a0, xv0.x, wq0); fma4(a0, xv0.y, wq1);
      fma4(a0, xv0.z, wq2); fma4(a0, xv0.w, wq3);
      fma4(a1, xv1.x, wq0); fma4(a1, xv1.y, wq1);
      fma4(a1, xv1.z, wq2); fma4(a1, xv1.w, wq3);
    }
    a0.x = xred(a0.x); a0.y = xred(a0.y); a0.z = xred(a0.z); a0.w = xred(a0.w);
    a1.x = xred(a1.x); a1.y = xred(a1.y); a1.z = xred(a1.z); a1.w = xred(a1.w);
    a0.x += bq.x; a0.y += bq.y; a0.z += bq.z; a0.w += bq.w;
    a1.x += bq.x; a1.y += bq.y; a1.z += bq.z; a1.w += bq.w;
    finish_token(n0, a0, lane, out, table, s_soft, s_hard);
    finish_token(n1, a1, lane, out, table, s_soft, s_hard);
  }
  __syncthreads();
  if (tid < NEXP) {
    atomicAdd(&ws[tid], s_soft[tid]);          // raw sums; scaled in combine
    atomicAdd(&ws[NEXP + tid], s_hard[tid]);
  }
}

extern "C" __global__ __launch_bounds__(256) void combine_kernel(
    const float* __restrict__ f, const float* __restrict__ ws,
    float* __restrict__ out) {
  __shared__ float part[DDIM*4];    // 12 KB -> 8 blocks/CU
  const int n   = blockIdx.x;
  const int tid = threadIdx.x;

  // finalize averages (gate finished: stream-ordered); soft|hard contiguous
  if (n == 0) {
    if (tid < 32) out[SOFT_OFF + tid] = ws[tid] * (1.0f/N_TOK);
    if (tid == 0) out[SCAL_OFF] = 0.0f;
  }

  f32x4 rec = ((const f32x4*)(ws + 32))[n];    // {e0,e1,w0,w1}, L2-hot
  int e0 = __float_as_int(rec.x);
  int e1 = __float_as_int(rec.y);
  float w0 = rec.z, w1 = rec.w;
  const int jg = (tid & 3) * 4;     // this thread's expert sub-quad
  float gx = (jg+0 == e0) ? w0 : ((jg+0 == e1) ? w1 : 0.0f);
  float gy = (jg+1 == e0) ? w0 : ((jg+1 == e1) ? w1 : 0.0f);
  float gz = (jg+2 == e0) ? w0 : ((jg+2 == e1) ? w1 : 0.0f);
  float gw = (jg+3 == e0) ? w0 : ((jg+3 == e1) ? w1 : 0.0f);

  // stream f[n,:,:]: 12 fully-coalesced 1KiB wave loads, partials to LDS
  const f32x4* fp = (const f32x4*)(f + (size_t)n * (DDIM*NEXP));
  #pragma unroll
  for (int k = 0; k < 12; ++k) {
    int q = tid + 256*k;
    f32x4 v = fp[q];
    part[q] = v.x*gx + v.y*gy + v.z*gz + v.w*gw;  // b32 contiguous: no conflict
  }
  __syncthreads();

  // transpose-reduce: b128 contiguous reads, full-wave coalesced 256B stores
  float* yr = out + (size_t)n * DDIM;
  #pragma unroll
  for (int i = 0; i < 3; ++i) {
    int d = tid + 256*i;
    f32x4 pv = ((const f32x4*)part)[d];
    yr[d] = (pv.x + pv.y) + (pv.z + pv.w);
  }
}

extern "C" void kernel_launch(void* const* d_in, const int* in_sizes, int n_in,
                              void* d_out, int out_size, void* d_ws, size_t ws_size,
                              hipStream_t stream) {
  const float* f = (const float*)d_in[0];   // [N, D, E]
  const float* x = (const float*)d_in[1];   // [N, D]
  const float* W = (const float*)d_in[2];   // [E, D]
  const float* b = (const float*)d_in[3];   // [E]
  float* out = (float*)d_out;
  float* ws  = (float*)d_ws;

  hipLaunchKernelGGL(init_ws_kernel, dim3(1), dim3(64), 0, stream, ws);
  hipLaunchKernelGGL(gate_kernel, dim3(512), dim3(256), 0, stream,
                     x, W, b, out, ws);
  hipLaunchKernelGGL(combine_kernel, dim3(N_TOK), dim3(256), 0, stream,
                     f, ws, out);
}